// Round 1
// baseline (562.827 us; speedup 1.0000x reference)
//
#include <hip/hip_runtime.h>
#include <hip/hip_bf16.h>

typedef __bf16 bf16;
typedef _Float16 f16;
typedef __bf16 v8bf __attribute__((ext_vector_type(8)));
typedef float v4f __attribute__((ext_vector_type(4)));

// ---------- constants ----------
#define DD 1024
#define LN_EPS 1e-5f

// output element offsets (all f32 in d_out)
#define O_Y     0
#define O_STATE 8192
#define O_IDXE  73728
#define O_RIDX  73792
#define O_WIDX  73824

// ws byte offsets (total 17404416 B — exact round-5/7 layout, proven in-bounds)
#define W_KV      0ull                      // bf16 [8][1032][1024] 16908288
#define W_STATE   16908288ull               // f32  [8][8][1024]      262144 (PoolA: u f32 then s bf16)
#define W_LATL    17170432ull               // f32  [8][1024]          32768
#define W_QLN     17203200ull               // f32  [8][1024]  (c0[64] reuses after k_qp)
#define W_R2      17235968ull               // f32  [1024]
#define W_RSC     17240064ull               // f32  [64]
#define W_SSC     17240320ull               // f32  [64]
#define W_OATT    17240576ull               // PoolB 160KB: qp / lg(f16 132KB) / o_attn+lat1..lat2
#define W_LAT1    17273344ull
#define W_LNFFN   17306112ull
#define W_H1      17338880ull
#define W_LAT2    17371648ull

__device__ __forceinline__ float wred_sum(float v) {
#pragma unroll
  for (int o = 32; o; o >>= 1) v += __shfl_down(v, o, 64);
  return v;
}

__device__ __forceinline__ void top4_of8(const float* sc, int* ridx) {
  unsigned used = 0;
#pragma unroll
  for (int k = 0; k < 4; k++) {
    float best = -3.4e38f; int bi = 0;
    for (int s = 0; s < 8; s++)
      if (!((used >> s) & 1) && sc[s] > best) { best = sc[s]; bi = s; }
    used |= 1u << bi; ridx[k] = bi;
  }
}

// ---------- r2 = row norms of A_skew ----------
__global__ __launch_bounds__(256) void k_r2(const float* __restrict__ A, float* __restrict__ r2) {
  int row = blockIdx.x, t = threadIdx.x;
  const float* p = A + (size_t)row * DD;
  float s = 0.f;
  for (int j = t; j < DD; j += 256) { float x = p[j]; s += x * x; }
  s = wred_sum(s);
  __shared__ float sh[4];
  if ((t & 63) == 0) sh[t >> 6] = s;
  __syncthreads();
  if (t == 0) r2[row] = sh[0] + sh[1] + sh[2] + sh[3];
}

// ---------- read_scores + slot_scores ----------
__global__ __launch_bounds__(256) void k_scores(const float* __restrict__ state,
    const float* __restrict__ W_rg, const float* __restrict__ g_sl, const float* __restrict__ b_sl,
    const float* __restrict__ W_sl, float* __restrict__ rsc, float* __restrict__ ssc) {
  int row = blockIdx.x, t = threadIdx.x, l = t & 63, w = t >> 6;
  const float* p = state + (size_t)row * DD;
  float x[4]; float sum = 0.f, sq = 0.f, rs = 0.f;
#pragma unroll
  for (int i = 0; i < 4; i++) {
    int j = t + i * 256;
    x[i] = p[j];
    sum += x[i]; sq += x[i] * x[i];
    rs += x[i] * W_rg[j];
  }
  __shared__ float sh[3][4];
  sum = wred_sum(sum); sq = wred_sum(sq); rs = wred_sum(rs);
  if (l == 0) { sh[0][w] = sum; sh[1][w] = sq; sh[2][w] = rs; }
  __syncthreads();
  float m = (sh[0][0] + sh[0][1] + sh[0][2] + sh[0][3]) * (1.0f / 1024.0f);
  float var = (sh[1][0] + sh[1][1] + sh[1][2] + sh[1][3]) * (1.0f / 1024.0f) - m * m;
  float rsTot = sh[2][0] + sh[2][1] + sh[2][2] + sh[2][3];
  float inv = 1.0f / sqrtf(var + LN_EPS);
  __syncthreads();
  float ss = 0.f;
#pragma unroll
  for (int i = 0; i < 4; i++) {
    int j = t + i * 256;
    float ln = (x[i] - m) * inv * g_sl[j] + b_sl[j];
    ss += ln * W_sl[j];
  }
  ss = wred_sum(ss);
  if (l == 0) sh[0][w] = ss;
  __syncthreads();
  if (t == 0) { rsc[row] = rsTot; ssc[row] = sh[0][0] + sh[0][1] + sh[0][2] + sh[0][3]; }
}

// ---------- gate: LN_moe + gate logits + top2 -> idx_experts, read_idx (f32 out) ----------
__global__ __launch_bounds__(256) void k_gate(const float* __restrict__ state,
    const float* __restrict__ rsc, const float* __restrict__ g_moe, const float* __restrict__ b_moe,
    const float* __restrict__ Wg, float* __restrict__ out) {
  int b = blockIdx.x >> 2, k = blockIdx.x & 3;
  int t = threadIdx.x, l = t & 63, w = t >> 6;
  __shared__ float rs[8];
  __shared__ float red[2][4];
  __shared__ float gl[8];
  if (t < 8) rs[t] = rsc[b * 8 + t];
  __syncthreads();
  int ridx[4]; top4_of8(rs, ridx);
  int s = ridx[k];
  const float* p = state + (size_t)(b * 8 + s) * DD;
  float x[4]; float sum = 0.f, sq = 0.f;
#pragma unroll
  for (int i = 0; i < 4; i++) {
    int j = t + i * 256;
    x[i] = p[j]; sum += x[i]; sq += x[i] * x[i];
  }
  sum = wred_sum(sum); sq = wred_sum(sq);
  if (l == 0) { red[0][w] = sum; red[1][w] = sq; }
  __syncthreads();
  float m = (red[0][0] + red[0][1] + red[0][2] + red[0][3]) * (1.0f / 1024.0f);
  float var = (red[1][0] + red[1][1] + red[1][2] + red[1][3]) * (1.0f / 1024.0f) - m * m;
  float inv = 1.0f / sqrtf(var + LN_EPS);
  float lnv[4];
#pragma unroll
  for (int i = 0; i < 4; i++) {
    int j = t + i * 256;
    lnv[i] = (x[i] - m) * inv * g_moe[j] + b_moe[j];
  }
  __syncthreads();
  for (int e = 0; e < 8; e++) {
    float acc = 0.f;
#pragma unroll
    for (int i = 0; i < 4; i++) acc += lnv[i] * Wg[(size_t)e * DD + t + i * 256];
    acc = wred_sum(acc);
    if (l == 0) red[0][w] = acc;
    __syncthreads();
    if (t == 0) gl[e] = red[0][0] + red[0][1] + red[0][2] + red[0][3];
    __syncthreads();
  }
  if (t == 0) {
    int e0 = 0, e1 = 0; float b0 = -3.4e38f, b1 = -3.4e38f;
    for (int e = 0; e < 8; e++) {
      float v = gl[e];
      if (v > b0) { b1 = b0; e1 = e0; b0 = v; e0 = e; }
      else if (v > b1) { b1 = v; e1 = e; }
    }
    out[O_IDXE + (b * 4 + k) * 2 + 0] = (float)e0;
    out[O_IDXE + (b * 4 + k) * 2 + 1] = (float)e1;
    if (k == 0)
      for (int kk = 0; kk < 4; kk++) out[O_RIDX + b * 4 + kk] = (float)ridx[kk];
  }
}

// ---------- state update (f32 out) ----------
__global__ __launch_bounds__(256) void k_state(const float* __restrict__ state_in,
    const float* __restrict__ rsc, const float* __restrict__ ssc, const float* __restrict__ r2,
    float* __restrict__ state_ws, float* __restrict__ out) {
  int b = blockIdx.x, t = threadIdx.x;
  __shared__ float rs[8];
  if (t < 8) rs[t] = rsc[b * 8 + t];
  __syncthreads();
  int ridx[4]; top4_of8(rs, ridx);
  float lr[4];
#pragma unroll
  for (int k = 0; k < 4; k++) lr[k] = ssc[b * 8 + ridx[k]];
  int w0 = 0, w1 = 0; float b0 = -3.4e38f, b1 = -3.4e38f;
#pragma unroll
  for (int k = 0; k < 4; k++) {
    float v = lr[k];
    if (v > b0) { b1 = b0; w1 = w0; b0 = v; w0 = k; }
    else if (v > b1) { b1 = v; w1 = k; }
  }
  int wid0 = ridx[w0], wid1 = ridx[w1];
  float mx = fmaxf(lr[0], lr[1]);
  float e0 = expf(lr[0] - mx), e1 = expf(lr[1] - mx);
  float den = e0 + e1;
  float ws0 = e0 / den, ws1 = e1 / den;
  float resid = 1.0f - (ws0 + ws1);
#pragma unroll
  for (int i = 0; i < 4; i++) {
    int j = t + i * 256;
    float q = 1.0f - 0.03125f * r2[j];  // diag Cayley, c=0.125, O(c^4) dropped
    float lca = 0.f;
#pragma unroll
    for (int k = 0; k < 4; k++)
      lca += tanhf(state_in[(size_t)(b * 8 + ridx[k]) * DD + j] * q);
    float tj = tanhf(lca * 0.25f);
#pragma unroll
    for (int s = 0; s < 8; s++) {
      float a = (s == wid0) ? ws0 : ((s == wid1) ? ws1 : 0.0f);
      float v = a * tj + resid * state_in[(size_t)(b * 8 + s) * DD + j];
      state_ws[(size_t)(b * 8 + s) * DD + j] = v;
      out[O_STATE + (size_t)(b * 8 + s) * DD + j] = v;
    }
  }
  if (t == 0) {
    out[O_WIDX + b * 2 + 0] = (float)wid0;
    out[O_WIDX + b * 2 + 1] = (float)wid1;
  }
}

// ---------- MFMA BT GEMM, f32 inputs, register-lean cvt staging, XCD swizzle ----------
// launch_bounds(256,2): grid is 512 blocks = 2 blocks/CU, so target exactly 2 waves/EU.
// This raises the register cap to 256/wave — the ~140 live regs (64 acc + 32 staged v4f +
// 32 frag + addr) fit with NO scratch spill. (Prior build: VGPR_Count=60, ~877MB of
// spill-eviction HBM writes per dispatch.)
// LDS row stride 56 bf16 (112B = 7x16B): keeps all v8bf accesses 16B-aligned and spreads
// fragment ds_read_b128 rows across all 32 banks (r*28 mod 32 tiles the banks over 8 rows)
// -> ~2-way instead of 8-way conflicts.
#define LDS_STRIDE 56
__global__ __launch_bounds__(256, 2) void k_gemm(const float* __restrict__ A,
    const float* __restrict__ Bm, const float* __restrict__ bias, bf16* __restrict__ kvbuf,
    float* __restrict__ lat_last) {
  __shared__ bf16 As[128 * LDS_STRIDE];
  __shared__ bf16 Bs[128 * LDS_STRIDE];
  const int t = threadIdx.x, l = t & 63, w = t >> 6;
  const int lin = blockIdx.y * 8 + blockIdx.x;
  const int mb = ((lin & 7) << 3) | ((lin >> 3) & 7);   // 8 A-band blocks per XCD
  const int nb = lin >> 6;
  const int mbase = mb * 128, nbase = nb * 128;
  const int wm = (w >> 1) * 64, wn = (w & 1) * 64;
  const int lm = l & 15, lk = (l >> 4) * 8;
  v4f acc[4][4];
#pragma unroll
  for (int i = 0; i < 4; i++)
#pragma unroll
    for (int j = 0; j < 4; j++) acc[i][j] = (v4f){0.f, 0.f, 0.f, 0.f};

  const int srow = t >> 2;          // 0..63
  const int skc = (t & 3) * 8;      // 0,8,16,24 (elements within BK=32)
  for (int k0 = 0; k0 < 1024; k0 += 32) {
    const float* ap0 = A + (size_t)(mbase + srow) * 1024 + k0 + skc;
    const float* ap1 = ap0 + (size_t)64 * 1024;
    const float* bp0 = Bm + (size_t)(nbase + srow) * 1024 + k0 + skc;
    const float* bp1 = bp0 + (size_t)64 * 1024;
    // named v4f registers — un-spillable, loads overlap previous iter's MFMA
    v4f a00 = *(const v4f*)ap0, a01 = *(const v4f*)(ap0 + 4);
    v4f a10 = *(const v4f*)ap1, a11 = *(const v4f*)(ap1 + 4);
    v4f b00 = *(const v4f*)bp0, b01 = *(const v4f*)(bp0 + 4);
    v4f b10 = *(const v4f*)bp1, b11 = *(const v4f*)(bp1 + 4);
    __syncthreads();
    v8bf pk;
#pragma unroll
    for (int r = 0; r < 4; r++) { pk[r] = (bf16)a00[r]; pk[4 + r] = (bf16)a01[r]; }
    *(v8bf*)(As + srow * LDS_STRIDE + skc) = pk;
#pragma unroll
    for (int r = 0; r < 4; r++) { pk[r] = (bf16)a10[r]; pk[4 + r] = (bf16)a11[r]; }
    *(v8bf*)(As + (srow + 64) * LDS_STRIDE + skc) = pk;
#pragma unroll
    for (int r = 0; r < 4; r++) { pk[r] = (bf16)b00[r]; pk[4 + r] = (bf16)b01[r]; }
    *(v8bf*)(Bs + srow * LDS_STRIDE + skc) = pk;
#pragma unroll
    for (int r = 0; r < 4; r++) { pk[r] = (bf16)b10[r]; pk[4 + r] = (bf16)b11[r]; }
    *(v8bf*)(Bs + (srow + 64) * LDS_STRIDE + skc) = pk;
    __syncthreads();
    v8bf af[4], bfr[4];
#pragma unroll
    for (int i = 0; i < 4; i++) af[i] = *(const v8bf*)(As + (wm + i * 16 + lm) * LDS_STRIDE + lk);
#pragma unroll
    for (int j = 0; j < 4; j++) bfr[j] = *(const v8bf*)(Bs + (wn + j * 16 + lm) * LDS_STRIDE + lk);
#pragma unroll
    for (int i = 0; i < 4; i++)
#pragma unroll
      for (int j = 0; j < 4; j++)
        acc[i][j] = __builtin_amdgcn_mfma_f32_16x16x32_bf16(af[i], bfr[j], acc[i][j], 0, 0, 0);
  }
#pragma unroll
  for (int i = 0; i < 4; i++)
#pragma unroll
    for (int j = 0; j < 4; j++)
#pragma unroll
      for (int r = 0; r < 4; r++) {
        int row = mbase + wm + i * 16 + (l >> 4) * 4 + r;
        int col = nbase + wn + j * 16 + lm;
        int tok = row & 1023, bb = row >> 10;
        int i2 = col & 511;                              // PE: base 8, half=512
        float f = exp2f((float)i2 * (3.0f / 512.0f));    // 8^(i2/512)
        float a = (float)tok / f;
        float pe = (col < 512) ? sinf(a) : cosf(a);
        float v = acc[i][j][r] + bias[col] + pe;
        kvbuf[((size_t)bb * 1032 + tok) * 1024 + col] = (bf16)v;
        if (tok == 1023) lat_last[(size_t)bb * 1024 + col] = v;
      }
}

// ---------- LN (in-place on kv token rows; state rows from f32; q row from f32 lat_last) ----------
__global__ __launch_bounds__(256) void k_ln(bf16* __restrict__ kvbuf,
    const float* __restrict__ state_ws, const float* __restrict__ gkv, const float* __restrict__ bkv,
    const float* __restrict__ gq, const float* __restrict__ bq,
    float* __restrict__ qln, const float* __restrict__ lat_last) {
  int r = blockIdx.x, t = threadIdx.x, l = t & 63, w = t >> 6;
  int b = r / 1032, p = r % 1032;
  bf16* row = kvbuf + ((size_t)b * 1032 + p) * DD;
  float x[4]; float sum = 0.f, sq = 0.f;
  if (p == 1023) {
    const float* src = lat_last + (size_t)b * DD;
#pragma unroll
    for (int i = 0; i < 4; i++) {
      int j = t + i * 256;
      x[i] = src[j]; sum += x[i]; sq += x[i] * x[i];
    }
  } else if (p < 1024) {
#pragma unroll
    for (int i = 0; i < 4; i++) {
      int j = t + i * 256;
      x[i] = (float)row[j]; sum += x[i]; sq += x[i] * x[i];
    }
  } else {
    const float* src = state_ws + ((size_t)b * 8 + (p - 1024)) * DD;
#pragma unroll
    for (int i = 0; i < 4; i++) {
      int j = t + i * 256;
      x[i] = src[j]; sum += x[i]; sq += x[i] * x[i];
    }
  }
  __shared__ float sh[2][4];
  sum = wred_sum(sum); sq = wred_sum(sq);
  if (l == 0) { sh[0][w] = sum; sh[1][w] = sq; }
  __syncthreads();
  float m = (sh[0][0] + sh[0][1] + sh[0][2] + sh[0][3]) * (1.0f / 1024.0f);
  float var = (sh[1][0] + sh[1][1] + sh[1][2] + sh[1][3]) * (1.0f / 1024.0f) - m * m;
  float inv = 1.0f / sqrtf(var + LN_EPS);
  if (p == 1023) {
#pragma unroll
    for (int i = 0; i < 4; i++) {
      int j = t + i * 256;
      qln[(size_t)b * DD + j] = (x[i] - m) * inv * gq[j] + bq[j];
    }
  }
#pragma unroll
  for (int i = 0; i < 4; i++) {
    int j = t + i * 256;
    row[j] = (bf16)((x[i] - m) * inv * gkv[j] + bkv[j]);
  }
}

// ---------- LN of one f32 row per block (ffn pre-LN) ----------
__global__ __launch_bounds__(256) void k_ln_row(const float* __restrict__ src,
    const float* __restrict__ g, const float* __restrict__ bb, float* __restrict__ dst) {
  int b = blockIdx.x, t = threadIdx.x, l = t & 63, w = t >> 6;
  const float* p = src + (size_t)b * DD;
  float x[4]; float sum = 0.f, sq = 0.f;
#pragma unroll
  for (int i = 0; i < 4; i++) {
    int j = t + i * 256;
    x[i] = p[j]; sum += x[i]; sq += x[i] * x[i];
  }
  __shared__ float sh[2][4];
  sum = wred_sum(sum); sq = wred_sum(sq);
  if (l == 0) { sh[0][w] = sum; sh[1][w] = sq; }
  __syncthreads();
  float m = (sh[0][0] + sh[0][1] + sh[0][2] + sh[0][3]) * (1.0f / 1024.0f);
  float var = (sh[1][0] + sh[1][1] + sh[1][2] + sh[1][3]) * (1.0f / 1024.0f) - m * m;
  float inv = 1.0f / sqrtf(var + LN_EPS);
#pragma unroll
  for (int i = 0; i < 4; i++) {
    int j = t + i * 256;
    dst[(size_t)b * DD + j] = (x[i] - m) * inv * g[j] + bb[j];
  }
}

// ---------- attention pipeline ----------
__global__ __launch_bounds__(256) void k_qp(const float* __restrict__ qln,
    const float* __restrict__ Wi, const float* __restrict__ bi, float* __restrict__ qp) {
  int idx = blockIdx.x * 4 + (threadIdx.x >> 6);
  int l = threadIdx.x & 63;
  int b = idx >> 10, n = idx & 1023;
  const float* xr = qln + (size_t)b * DD;
  const float* wr = Wi + (size_t)n * DD;
  float acc = 0.f;
#pragma unroll
  for (int k0 = 0; k0 < 1024; k0 += 64) acc += xr[k0 + l] * wr[k0 + l];
  acc = wred_sum(acc);
  if (l == 0) qp[idx] = acc + bi[n];
}

__global__ __launch_bounds__(256) void k_c0(const float* __restrict__ qp,
    const float* __restrict__ bi, float* __restrict__ c0) {
  int t = threadIdx.x;
  if (t < 64) {
    int b = t >> 3, h = t & 7;
    float a = 0.f;
#pragma unroll 8
    for (int d = 0; d < 128; d++)
      a += qp[b * 1024 + h * 128 + d] * bi[1024 + h * 128 + d];
    c0[t] = a;
  }
}

__global__ __launch_bounds__(256) void k_u(const float* __restrict__ qp,
    const float* __restrict__ Wi, float* __restrict__ u) {
  int h = blockIdx.x >> 4, kt = blockIdx.x & 15;
  int t = threadIdx.x;
  __shared__ float qs[8][128];
#pragma unroll
  for (int i = 0; i < 4; i++) {
    int f = t * 4 + i;
    int b = f >> 7, d = f & 127;
    qs[b][d] = qp[b * 1024 + h * 128 + d];
  }
  __syncthreads();
  int k = kt * 64 + (t & 63);
  int bh = t >> 6;
  const float* wkb = Wi + (size_t)(1024 + h * 128) * DD + k;
  float a0 = 0.f, a1 = 0.f;
#pragma unroll 8
  for (int d = 0; d < 128; d++) {
    float wv = wkb[(size_t)d * DD];
    a0 += qs[bh][d] * wv;
    a1 += qs[bh + 4][d] * wv;
  }
  u[(size_t)(bh * 8 + h) * DD + k] = a0;
  u[(size_t)((bh + 4) * 8 + h) * DD + k] = a1;
}

__global__ __launch_bounds__(256) void k_lg(const float* __restrict__ u,
    const bf16* __restrict__ kvbuf, const float* __restrict__ c0, f16* __restrict__ lg) {
  int b = blockIdx.x / 33, tile = blockIdx.x % 33;
  int p0 = tile * 32, t = threadIdx.x;
  __shared__ bf16 kvs[32 * 1032];
  __shared__ float us[8 * 1032];
  const bf16* kvb = kvbuf + (size_t)b * 1032 * DD;
#pragma unroll
  for (int i = 0; i < 16; i++) {
    int flat = (i * 256 + t) * 8;
    int row = flat >> 10, col = flat & 1023;
    int gp = p0 + row; if (gp > 1031) gp = 1031;
    *(v8bf*)(kvs + row * 1032 + col) = *(const v8bf*)(kvb + (size_t)gp * DD + col);
  }
#pragma unroll
  for (int i = 0; i < 8; i++) {
    int flat = (i * 256 + t) * 4;
    int row = flat >> 10, col = flat & 1023;
    *(v4f*)(us + row * 1032 + col) = *(const v4f*)(u + (size_t)(b * 8 + row) * DD + col);
  }
  __syncthreads();
  int pl = t >> 3, h = t & 7;
  if (p0 + pl < 1032) {
    float acc = 0.f;
#pragma unroll
    for (int k = 0; k < 1024; k += 8) {
      v8bf kv8 = *(const v8bf*)(kvs + pl * 1032 + k);
#pragma unroll
      for (int j = 0; j < 8; j++) acc += us[h * 1032 + k + j] * (float)kv8[j];
    }
    lg[(size_t)(b * 8 + h) * 1032 + p0 + pl] =
        (f16)((acc + c0[b * 8 + h]) * 0.08838834764831845f);
  }
}

__global__ __launch_bounds__(256) void k_sm(f16* __restrict__ lg) {
  int t = threadIdx.x, l = t & 63, w = t >> 6;
  f16* p = lg + (size_t)blockIdx.x * 1032;
  float x[5];
  float mx = -3.4e38f;
#pragma unroll
  for (int i = 0; i < 5; i++) {
    int idx = t + i * 256;
    if (idx < 1032) { x[i] = (float)p[idx]; mx = fmaxf(mx, x[i]); }
  }
  __shared__ float sh[4];
#pragma unroll
  for (int o = 32; o; o >>= 1) mx = fmaxf(mx, __shfl_down(mx, o, 64));
  if (l == 0) sh[w] = mx;
  __syncthreads();
  mx = fmaxf(fmaxf(sh[0], sh[1]), fmaxf(sh[2], sh[3]));
  __syncthreads();
  float sum = 0.f;
#pragma unroll
  for (int i = 0; i < 5; i++) {
    int idx = t + i * 256;
    if (idx < 1032) { x[i] = expf(x[i] - mx); sum += x[i]; }
  }
  sum = wred_sum(sum);
  if (l == 0) sh[w] = sum;
  __syncthreads();
  float inv = 1.0f / (sh[0] + sh[1] + sh[2] + sh[3]);
#pragma unroll
  for (int i = 0; i < 5; i++) {
    int idx = t + i * 256;
    if (idx < 1032) p[idx] = (f16)(x[i] * inv);
  }
}

__global__ __launch_bounds__(256) void k_s(const f16* __restrict__ lg,
    const bf16* __restrict__ kvbuf, bf16* __restrict__ s) {
  int b = blockIdx.x >> 4, kt = blockIdx.x & 15;
  int t = threadIdx.x;
  __shared__ f16 wl[8 * 1040];
  for (int h = 0; h < 8; h++)
    for (int i = t; i < 1032; i += 256)
      wl[h * 1040 + i] = lg[(size_t)(b * 8 + h) * 1032 + i];
  __syncthreads();
  int k = kt * 64 + (t & 63), h0 = t >> 6;
  const bf16* kvb = kvbuf + (size_t)b * 1032 * DD + k;
  float a0 = 0.f, a1 = 0.f;
#pragma unroll 4
  for (int p = 0; p < 1032; p++) {
    float kvv = (float)kvb[(size_t)p * DD];
    a0 += (float)wl[h0 * 1040 + p] * kvv;
    a1 += (float)wl[(h0 + 4) * 1040 + p] * kvv;
  }
  s[(size_t)(b * 8 + h0) * DD + k] = (bf16)a0;
  s[(size_t)(b * 8 + h0 + 4) * DD + k] = (bf16)a1;
}

__global__ __launch_bounds__(256) void k_ov(const bf16* __restrict__ s,
    const float* __restrict__ Wi, const float* __restrict__ bi, float* __restrict__ o) {
  int idx = blockIdx.x * 4 + (threadIdx.x >> 6);
  int l = threadIdx.x & 63;
  int b = idx >> 10, n = idx & 1023, h = n >> 7;
  const bf16* sr = s + (size_t)(b * 8 + h) * DD;
  const float* wr = Wi + (size_t)(2048 + n) * DD;
  float acc = 0.f;
#pragma unroll
  for (int k0 = 0; k0 < 1024; k0 += 64) acc += (float)sr[k0 + l] * wr[k0 + l];
  acc = wred_sum(acc);
  if (l == 0) o[idx] = acc + bi[2048 + n];
}

// ---------- tail GEMVs ----------
template <int MODE>
__global__ __launch_bounds__(256) void k_gemv(const float* __restrict__ xin,
    const float* __restrict__ W, const float* __restrict__ bias,
    const float* __restrict__ res, float* __restrict__ outf) {
  int idx = blockIdx.x * 4 + (threadIdx.x >> 6);
  int l = threadIdx.x & 63;
  int b = idx >> 10, n = idx & 1023;
  const float* xr = xin + (size_t)b * DD;
  const float* wr = W + (size_t)n * DD;
  float acc = 0.f;
#pragma unroll
  for (int k0 = 0; k0 < 1024; k0 += 64) acc += xr[k0 + l] * wr[k0 + l];
  acc = wred_sum(acc);
  if (l == 0) {
    float v = acc + bias[n];
    if (MODE == 0) outf[idx] = res[idx] + v;
    if (MODE == 1) outf[idx] = 0.5f * v * (1.0f + erff(v * 0.70710678118654752f));
    if (MODE == 2) outf[idx] = res[idx] + v;
    if (MODE == 3) outf[O_Y + idx] = v;
  }
}

extern "C" void kernel_launch(void* const* d_in, const int* in_sizes, int n_in,
                              void* d_out, int out_size, void* d_ws, size_t ws_size,
                              hipStream_t stream) {
  const float* x        = (const float*)d_in[0];
  const float* state_in = (const float*)d_in[1];
  const float* W_rg     = (const float*)d_in[2];
  const float* ln_moe_g = (const float*)d_in[3];
  const float* ln_moe_b = (const float*)d_in[4];
  const float* W_gate   = (const float*)d_in[5];
  const float* A_skew   = (const float*)d_in[6];
  const float* ln_sl_g  = (const float*)d_in[7];
  const float* ln_sl_b  = (const float*)d_in[8];
  const float* W_slot   = (const float*)d_in[9];
  const float* W_oe     = (const float*)d_in[10];
  const float* b_oe     = (const float*)d_in[11];
  const float* ln_q_g   = (const float*)d_in[12];
  const float* ln_q_b   = (const float*)d_in[13];
  const float* ln_kv_g  = (const float*)d_in[14];
  const float* ln_kv_b  = (const float*)d_in[15];
  const float* in_w     = (const float*)d_in[16];
  const float* in_b     = (const float*)d_in[17];
  const float* out_w    = (const float*)d_in[18];
  const float* out_b    = (const float*)d_in[19];
  const float* ln_f_g   = (const float*)d_in[20];
  const float* ln_f_b   = (const float*)d_in[21];
  const float* W_fc1    = (const float*)d_in[22];
  const float* b_fc1    = (const float*)d_in[23];
  const float* W_fc2    = (const float*)d_in[24];
  const float* b_fc2    = (const float*)d_in[25];
  const float* W_out    = (const float*)d_in[26];
  const float* b_out    = (const float*)d_in[27];

  char* ws = (char*)d_ws;
  bf16*  kvbuf    = (bf16*)(ws + W_KV);
  float* state_ws = (float*)(ws + W_STATE);
  float* u_buf    = (float*)(ws + W_STATE);
  bf16*  s_buf    = (bf16*)(ws + W_STATE);
  float* lat_last = (float*)(ws + W_LATL);
  float* qln      = (float*)(ws + W_QLN);
  float* c0       = (float*)(ws + W_QLN);
  float* r2       = (float*)(ws + W_R2);
  float* rsc      = (float*)(ws + W_RSC);
  float* ssc      = (float*)(ws + W_SSC);
  float* qp       = (float*)(ws + W_OATT);
  f16*   lg       = (f16*)(ws + W_OATT);
  float* o_attn   = (float*)(ws + W_OATT);
  float* lat1     = (float*)(ws + W_LAT1);
  float* lnffn    = (float*)(ws + W_LNFFN);
  float* h1       = (float*)(ws + W_H1);
  float* lat2     = (float*)(ws + W_LAT2);
  float* out = (float*)d_out;

  k_r2<<<1024, 256, 0, stream>>>(A_skew, r2);
  k_scores<<<64, 256, 0, stream>>>(state_in, W_rg, ln_sl_g, ln_sl_b, W_slot, rsc, ssc);
  k_gate<<<32, 256, 0, stream>>>(state_in, rsc, ln_moe_g, ln_moe_b, W_gate, out);
  k_state<<<8, 256, 0, stream>>>(state_in, rsc, ssc, r2, state_ws, out);
  k_gemm<<<dim3(8, 64), 256, 0, stream>>>(x, W_oe, b_oe, kvbuf, lat_last);
  k_ln<<<8256, 256, 0, stream>>>(kvbuf, state_ws, ln_kv_g, ln_kv_b, ln_q_g, ln_q_b, qln, lat_last);
  k_qp<<<2048, 256, 0, stream>>>(qln, in_w, in_b, qp);
  k_c0<<<1, 256, 0, stream>>>(qp, in_b, c0);
  k_u<<<128, 256, 0, stream>>>(qp, in_w, u_buf);
  k_lg<<<264, 256, 0, stream>>>(u_buf, kvbuf, c0, lg);
  k_sm<<<64, 256, 0, stream>>>(lg);
  k_s<<<128, 256, 0, stream>>>(lg, kvbuf, s_buf);
  k_ov<<<2048, 256, 0, stream>>>(s_buf, in_w, in_b, o_attn);
  k_gemv<0><<<2048, 256, 0, stream>>>(o_attn, out_w, out_b, lat_last, lat1);
  k_ln_row<<<8, 256, 0, stream>>>(lat1, ln_f_g, ln_f_b, lnffn);
  k_gemv<1><<<2048, 256, 0, stream>>>(lnffn, W_fc1, b_fc1, nullptr, h1);
  k_gemv<2><<<2048, 256, 0, stream>>>(h1, W_fc2, b_fc2, lat1, lat2);
  k_gemv<3><<<2048, 256, 0, stream>>>(lat2, W_out, b_out, nullptr, out);
}

// Round 2
// 557.360 us; speedup vs baseline: 1.0098x; 1.0098x over previous
//
#include <hip/hip_runtime.h>
#include <hip/hip_bf16.h>

typedef __bf16 bf16;
typedef _Float16 f16;
typedef __bf16 v8bf __attribute__((ext_vector_type(8)));
typedef float v4f __attribute__((ext_vector_type(4)));

// ---------- constants ----------
#define DD 1024
#define LN_EPS 1e-5f

// output element offsets (all f32 in d_out)
#define O_Y     0
#define O_STATE 8192
#define O_IDXE  73728
#define O_RIDX  73792
#define O_WIDX  73824

// ws byte offsets (total 17404416 B — exact round-5/7 layout, proven in-bounds)
#define W_KV      0ull                      // bf16 [8][1032][1024] 16908288
#define W_STATE   16908288ull               // f32  [8][8][1024]      262144 (PoolA: u f32 then s bf16)
#define W_LATL    17170432ull               // f32  [8][1024]          32768
#define W_QLN     17203200ull               // f32  [8][1024]  (c0[64] reuses after k_qp)
#define W_R2      17235968ull               // f32  [1024]
#define W_RSC     17240064ull               // f32  [64]
#define W_SSC     17240320ull               // f32  [64]
#define W_OATT    17240576ull               // PoolB 160KB: qp / lg(f16 132KB) / o_attn+lat1..lat2
#define W_LAT1    17273344ull
#define W_LNFFN   17306112ull
#define W_H1      17338880ull
#define W_LAT2    17371648ull

__device__ __forceinline__ float wred_sum(float v) {
#pragma unroll
  for (int o = 32; o; o >>= 1) v += __shfl_down(v, o, 64);
  return v;
}

__device__ __forceinline__ void top4_of8(const float* sc, int* ridx) {
  unsigned used = 0;
#pragma unroll
  for (int k = 0; k < 4; k++) {
    float best = -3.4e38f; int bi = 0;
    for (int s = 0; s < 8; s++)
      if (!((used >> s) & 1) && sc[s] > best) { best = sc[s]; bi = s; }
    used |= 1u << bi; ridx[k] = bi;
  }
}

// ---------- r2 = row norms of A_skew ----------
__global__ __launch_bounds__(256) void k_r2(const float* __restrict__ A, float* __restrict__ r2) {
  int row = blockIdx.x, t = threadIdx.x;
  const float* p = A + (size_t)row * DD;
  float s = 0.f;
  for (int j = t; j < DD; j += 256) { float x = p[j]; s += x * x; }
  s = wred_sum(s);
  __shared__ float sh[4];
  if ((t & 63) == 0) sh[t >> 6] = s;
  __syncthreads();
  if (t == 0) r2[row] = sh[0] + sh[1] + sh[2] + sh[3];
}

// ---------- read_scores + slot_scores ----------
__global__ __launch_bounds__(256) void k_scores(const float* __restrict__ state,
    const float* __restrict__ W_rg, const float* __restrict__ g_sl, const float* __restrict__ b_sl,
    const float* __restrict__ W_sl, float* __restrict__ rsc, float* __restrict__ ssc) {
  int row = blockIdx.x, t = threadIdx.x, l = t & 63, w = t >> 6;
  const float* p = state + (size_t)row * DD;
  float x[4]; float sum = 0.f, sq = 0.f, rs = 0.f;
#pragma unroll
  for (int i = 0; i < 4; i++) {
    int j = t + i * 256;
    x[i] = p[j];
    sum += x[i]; sq += x[i] * x[i];
    rs += x[i] * W_rg[j];
  }
  __shared__ float sh[3][4];
  sum = wred_sum(sum); sq = wred_sum(sq); rs = wred_sum(rs);
  if (l == 0) { sh[0][w] = sum; sh[1][w] = sq; sh[2][w] = rs; }
  __syncthreads();
  float m = (sh[0][0] + sh[0][1] + sh[0][2] + sh[0][3]) * (1.0f / 1024.0f);
  float var = (sh[1][0] + sh[1][1] + sh[1][2] + sh[1][3]) * (1.0f / 1024.0f) - m * m;
  float rsTot = sh[2][0] + sh[2][1] + sh[2][2] + sh[2][3];
  float inv = 1.0f / sqrtf(var + LN_EPS);
  __syncthreads();
  float ss = 0.f;
#pragma unroll
  for (int i = 0; i < 4; i++) {
    int j = t + i * 256;
    float ln = (x[i] - m) * inv * g_sl[j] + b_sl[j];
    ss += ln * W_sl[j];
  }
  ss = wred_sum(ss);
  if (l == 0) sh[0][w] = ss;
  __syncthreads();
  if (t == 0) { rsc[row] = rsTot; ssc[row] = sh[0][0] + sh[0][1] + sh[0][2] + sh[0][3]; }
}

// ---------- gate: LN_moe + gate logits + top2 -> idx_experts, read_idx (f32 out) ----------
__global__ __launch_bounds__(256) void k_gate(const float* __restrict__ state,
    const float* __restrict__ rsc, const float* __restrict__ g_moe, const float* __restrict__ b_moe,
    const float* __restrict__ Wg, float* __restrict__ out) {
  int b = blockIdx.x >> 2, k = blockIdx.x & 3;
  int t = threadIdx.x, l = t & 63, w = t >> 6;
  __shared__ float rs[8];
  __shared__ float red[2][4];
  __shared__ float gl[8];
  if (t < 8) rs[t] = rsc[b * 8 + t];
  __syncthreads();
  int ridx[4]; top4_of8(rs, ridx);
  int s = ridx[k];
  const float* p = state + (size_t)(b * 8 + s) * DD;
  float x[4]; float sum = 0.f, sq = 0.f;
#pragma unroll
  for (int i = 0; i < 4; i++) {
    int j = t + i * 256;
    x[i] = p[j]; sum += x[i]; sq += x[i] * x[i];
  }
  sum = wred_sum(sum); sq = wred_sum(sq);
  if (l == 0) { red[0][w] = sum; red[1][w] = sq; }
  __syncthreads();
  float m = (red[0][0] + red[0][1] + red[0][2] + red[0][3]) * (1.0f / 1024.0f);
  float var = (red[1][0] + red[1][1] + red[1][2] + red[1][3]) * (1.0f / 1024.0f) - m * m;
  float inv = 1.0f / sqrtf(var + LN_EPS);
  float lnv[4];
#pragma unroll
  for (int i = 0; i < 4; i++) {
    int j = t + i * 256;
    lnv[i] = (x[i] - m) * inv * g_moe[j] + b_moe[j];
  }
  __syncthreads();
  for (int e = 0; e < 8; e++) {
    float acc = 0.f;
#pragma unroll
    for (int i = 0; i < 4; i++) acc += lnv[i] * Wg[(size_t)e * DD + t + i * 256];
    acc = wred_sum(acc);
    if (l == 0) red[0][w] = acc;
    __syncthreads();
    if (t == 0) gl[e] = red[0][0] + red[0][1] + red[0][2] + red[0][3];
    __syncthreads();
  }
  if (t == 0) {
    int e0 = 0, e1 = 0; float b0 = -3.4e38f, b1 = -3.4e38f;
    for (int e = 0; e < 8; e++) {
      float v = gl[e];
      if (v > b0) { b1 = b0; e1 = e0; b0 = v; e0 = e; }
      else if (v > b1) { b1 = v; e1 = e; }
    }
    out[O_IDXE + (b * 4 + k) * 2 + 0] = (float)e0;
    out[O_IDXE + (b * 4 + k) * 2 + 1] = (float)e1;
    if (k == 0)
      for (int kk = 0; kk < 4; kk++) out[O_RIDX + b * 4 + kk] = (float)ridx[kk];
  }
}

// ---------- state update (f32 out) ----------
__global__ __launch_bounds__(256) void k_state(const float* __restrict__ state_in,
    const float* __restrict__ rsc, const float* __restrict__ ssc, const float* __restrict__ r2,
    float* __restrict__ state_ws, float* __restrict__ out) {
  int b = blockIdx.x, t = threadIdx.x;
  __shared__ float rs[8];
  if (t < 8) rs[t] = rsc[b * 8 + t];
  __syncthreads();
  int ridx[4]; top4_of8(rs, ridx);
  float lr[4];
#pragma unroll
  for (int k = 0; k < 4; k++) lr[k] = ssc[b * 8 + ridx[k]];
  int w0 = 0, w1 = 0; float b0 = -3.4e38f, b1 = -3.4e38f;
#pragma unroll
  for (int k = 0; k < 4; k++) {
    float v = lr[k];
    if (v > b0) { b1 = b0; w1 = w0; b0 = v; w0 = k; }
    else if (v > b1) { b1 = v; w1 = k; }
  }
  int wid0 = ridx[w0], wid1 = ridx[w1];
  float mx = fmaxf(lr[0], lr[1]);
  float e0 = expf(lr[0] - mx), e1 = expf(lr[1] - mx);
  float den = e0 + e1;
  float ws0 = e0 / den, ws1 = e1 / den;
  float resid = 1.0f - (ws0 + ws1);
#pragma unroll
  for (int i = 0; i < 4; i++) {
    int j = t + i * 256;
    float q = 1.0f - 0.03125f * r2[j];  // diag Cayley, c=0.125, O(c^4) dropped
    float lca = 0.f;
#pragma unroll
    for (int k = 0; k < 4; k++)
      lca += tanhf(state_in[(size_t)(b * 8 + ridx[k]) * DD + j] * q);
    float tj = tanhf(lca * 0.25f);
#pragma unroll
    for (int s = 0; s < 8; s++) {
      float a = (s == wid0) ? ws0 : ((s == wid1) ? ws1 : 0.0f);
      float v = a * tj + resid * state_in[(size_t)(b * 8 + s) * DD + j];
      state_ws[(size_t)(b * 8 + s) * DD + j] = v;
      out[O_STATE + (size_t)(b * 8 + s) * DD + j] = v;
    }
  }
  if (t == 0) {
    out[O_WIDX + b * 2 + 0] = (float)wid0;
    out[O_WIDX + b * 2 + 1] = (float)wid1;
  }
}

// ---------- MFMA BT GEMM, f32 inputs, cvt staging, XCD swizzle ----------
// Round-2 changes vs round-1:
//  (1) EPILOGUE: stage the 128x128 out-tile through LDS (reusing As, 4 slabs of
//      32 rows x 128 cols = 8KB) and store 32 CONTIGUOUS bytes/lane -> every
//      wave-store is 8 full 256B row segments. Round-1's 64 scalar 2B scattered
//      stores/thread reached HBM as ~64-128B sector transactions each
//      (~900MB WRITE_SIZE = 53x amplification, write-BW-bound at 3.6TB/s).
//  (2) LDS chunk-XOR swizzle: chunk' = chunk ^ ((row>>1)&3) on both ds_write and
//      fragment ds_read -> <=2-way bank aliasing (free per m136). Round-1's
//      stride-56 pad was wrong (doubled conflicts); reverted to stride 32.
//  (3) A-then-B cvt staging (peak live staged regs 24 instead of 32).
__global__ __launch_bounds__(256, 2) void k_gemm(const float* __restrict__ A,
    const float* __restrict__ Bm, const float* __restrict__ bias, bf16* __restrict__ kvbuf,
    float* __restrict__ lat_last) {
  __shared__ bf16 As[128 * 32];
  __shared__ bf16 Bs[128 * 32];
  const int t = threadIdx.x, l = t & 63, w = t >> 6;
  const int lin = blockIdx.y * 8 + blockIdx.x;
  const int mb = ((lin & 7) << 3) | ((lin >> 3) & 7);   // 8 A-band blocks per XCD
  const int nb = lin >> 6;
  const int mbase = mb * 128, nbase = nb * 128;
  const int wm = (w >> 1) * 64, wn = (w & 1) * 64;
  const int lm = l & 15, lk4 = l >> 4;                  // lk4 = fragment chunk 0..3
  v4f acc[4][4];
#pragma unroll
  for (int i = 0; i < 4; i++)
#pragma unroll
    for (int j = 0; j < 4; j++) acc[i][j] = (v4f){0.f, 0.f, 0.f, 0.f};

  const int srow = t >> 2;          // 0..63
  const int sch = t & 3;            // staging chunk 0..3 (8 bf16 each)
  // swizzled element offsets (row>>1 identical for srow and srow+64: 64 = 0 mod 8 after >>1&3? (srow+64)>>1 = srow>>1+32, &3 same)
  const int swA0 = srow * 32 + (sch ^ ((srow >> 1) & 3)) * 8;
  const int swA1 = (srow + 64) * 32 + (sch ^ (((srow + 64) >> 1) & 3)) * 8;

  for (int k0 = 0; k0 < 1024; k0 += 32) {
    const float* ap0 = A + (size_t)(mbase + srow) * 1024 + k0 + sch * 8;
    const float* ap1 = ap0 + (size_t)64 * 1024;
    const float* bp0 = Bm + (size_t)(nbase + srow) * 1024 + k0 + sch * 8;
    const float* bp1 = bp0 + (size_t)64 * 1024;
    // A loads + cvt first, then B: peak live staged registers ~24 not 32
    v4f a00 = *(const v4f*)ap0, a01 = *(const v4f*)(ap0 + 4);
    v4f a10 = *(const v4f*)ap1, a11 = *(const v4f*)(ap1 + 4);
    v8bf pa0, pa1;
#pragma unroll
    for (int r = 0; r < 4; r++) { pa0[r] = (bf16)a00[r]; pa0[4 + r] = (bf16)a01[r]; }
#pragma unroll
    for (int r = 0; r < 4; r++) { pa1[r] = (bf16)a10[r]; pa1[4 + r] = (bf16)a11[r]; }
    v4f b00 = *(const v4f*)bp0, b01 = *(const v4f*)(bp0 + 4);
    v4f b10 = *(const v4f*)bp1, b11 = *(const v4f*)(bp1 + 4);
    v8bf pb0, pb1;
#pragma unroll
    for (int r = 0; r < 4; r++) { pb0[r] = (bf16)b00[r]; pb0[4 + r] = (bf16)b01[r]; }
#pragma unroll
    for (int r = 0; r < 4; r++) { pb1[r] = (bf16)b10[r]; pb1[4 + r] = (bf16)b11[r]; }
    __syncthreads();
    *(v8bf*)(As + swA0) = pa0;
    *(v8bf*)(As + swA1) = pa1;
    *(v8bf*)(Bs + swA0) = pb0;
    *(v8bf*)(Bs + swA1) = pb1;
    __syncthreads();
    v8bf af[4], bfr[4];
#pragma unroll
    for (int i = 0; i < 4; i++) {
      int R = wm + i * 16 + lm;
      af[i] = *(const v8bf*)(As + R * 32 + (lk4 ^ ((R >> 1) & 3)) * 8);
    }
#pragma unroll
    for (int j = 0; j < 4; j++) {
      int R = wn + j * 16 + lm;
      bfr[j] = *(const v8bf*)(Bs + R * 32 + (lk4 ^ ((R >> 1) & 3)) * 8);
    }
#pragma unroll
    for (int i = 0; i < 4; i++)
#pragma unroll
      for (int j = 0; j < 4; j++)
        acc[i][j] = __builtin_amdgcn_mfma_f32_16x16x32_bf16(af[i], bfr[j], acc[i][j], 0, 0, 0);
  }

  // ---- epilogue: LDS-staged coalesced stores (reuse As: 32 rows x 128 cols = 8KB) ----
  bf16* ot = As;
  const int band = w >> 1;          // 0: rows wm=0 band, 1: rows wm=64 band
#pragma unroll 1
  for (int i = 0; i < 4; i++) {
    __syncthreads();                // prev slab's reads (or K-loop frag reads) done
#pragma unroll
    for (int j = 0; j < 4; j++)
#pragma unroll
      for (int r = 0; r < 4; r++) {
        int lrow = band * 16 + (l >> 4) * 4 + r;        // 0..31
        int lcol = wn + j * 16 + lm;                    // 0..127
        int grow = mbase + band * 64 + i * 16 + (l >> 4) * 4 + r;
        int col = nbase + lcol;
        int tok = grow & 1023, bb = grow >> 10;
        int i2 = col & 511;                             // PE: base 8, half=512
        float f = exp2f((float)i2 * (3.0f / 512.0f));   // 8^(i2/512)
        float a = (float)tok / f;
        float pe = (col < 512) ? sinf(a) : cosf(a);
        float v = acc[i][j][r] + bias[col] + pe;
        ot[lrow * 128 + lcol] = (bf16)v;
        if (tok == 1023) lat_last[(size_t)bb * 1024 + col] = v;
      }
    __syncthreads();
    // coalesced flush: thread t -> row t>>3 (0..31), 32B at col (t&7)*16
    {
      int rr = t >> 3;
      int cc = (t & 7) * 16;
      int grow = mbase + (rr >> 4) * 64 + i * 16 + (rr & 15);
      int tok = grow & 1023, bb = grow >> 10;
      v8bf d0 = *(const v8bf*)(ot + rr * 128 + cc);
      v8bf d1 = *(const v8bf*)(ot + rr * 128 + cc + 8);
      bf16* dst = kvbuf + ((size_t)bb * 1032 + tok) * 1024 + nbase + cc;
      *(v8bf*)dst = d0;
      *(v8bf*)(dst + 8) = d1;
    }
  }
}

// ---------- LN (in-place on kv token rows; state rows from f32; q row from f32 lat_last) ----------
__global__ __launch_bounds__(256) void k_ln(bf16* __restrict__ kvbuf,
    const float* __restrict__ state_ws, const float* __restrict__ gkv, const float* __restrict__ bkv,
    const float* __restrict__ gq, const float* __restrict__ bq,
    float* __restrict__ qln, const float* __restrict__ lat_last) {
  int r = blockIdx.x, t = threadIdx.x, l = t & 63, w = t >> 6;
  int b = r / 1032, p = r % 1032;
  bf16* row = kvbuf + ((size_t)b * 1032 + p) * DD;
  float x[4]; float sum = 0.f, sq = 0.f;
  if (p == 1023) {
    const float* src = lat_last + (size_t)b * DD;
#pragma unroll
    for (int i = 0; i < 4; i++) {
      int j = t + i * 256;
      x[i] = src[j]; sum += x[i]; sq += x[i] * x[i];
    }
  } else if (p < 1024) {
#pragma unroll
    for (int i = 0; i < 4; i++) {
      int j = t + i * 256;
      x[i] = (float)row[j]; sum += x[i]; sq += x[i] * x[i];
    }
  } else {
    const float* src = state_ws + ((size_t)b * 8 + (p - 1024)) * DD;
#pragma unroll
    for (int i = 0; i < 4; i++) {
      int j = t + i * 256;
      x[i] = src[j]; sum += x[i]; sq += x[i] * x[i];
    }
  }
  __shared__ float sh[2][4];
  sum = wred_sum(sum); sq = wred_sum(sq);
  if (l == 0) { sh[0][w] = sum; sh[1][w] = sq; }
  __syncthreads();
  float m = (sh[0][0] + sh[0][1] + sh[0][2] + sh[0][3]) * (1.0f / 1024.0f);
  float var = (sh[1][0] + sh[1][1] + sh[1][2] + sh[1][3]) * (1.0f / 1024.0f) - m * m;
  float inv = 1.0f / sqrtf(var + LN_EPS);
  if (p == 1023) {
#pragma unroll
    for (int i = 0; i < 4; i++) {
      int j = t + i * 256;
      qln[(size_t)b * DD + j] = (x[i] - m) * inv * gq[j] + bq[j];
    }
  }
#pragma unroll
  for (int i = 0; i < 4; i++) {
    int j = t + i * 256;
    row[j] = (bf16)((x[i] - m) * inv * gkv[j] + bkv[j]);
  }
}

// ---------- LN of one f32 row per block (ffn pre-LN) ----------
__global__ __launch_bounds__(256) void k_ln_row(const float* __restrict__ src,
    const float* __restrict__ g, const float* __restrict__ bb, float* __restrict__ dst) {
  int b = blockIdx.x, t = threadIdx.x, l = t & 63, w = t >> 6;
  const float* p = src + (size_t)b * DD;
  float x[4]; float sum = 0.f, sq = 0.f;
#pragma unroll
  for (int i = 0; i < 4; i++) {
    int j = t + i * 256;
    x[i] = p[j]; sum += x[i]; sq += x[i] * x[i];
  }
  __shared__ float sh[2][4];
  sum = wred_sum(sum); sq = wred_sum(sq);
  if (l == 0) { sh[0][w] = sum; sh[1][w] = sq; }
  __syncthreads();
  float m = (sh[0][0] + sh[0][1] + sh[0][2] + sh[0][3]) * (1.0f / 1024.0f);
  float var = (sh[1][0] + sh[1][1] + sh[1][2] + sh[1][3]) * (1.0f / 1024.0f) - m * m;
  float inv = 1.0f / sqrtf(var + LN_EPS);
#pragma unroll
  for (int i = 0; i < 4; i++) {
    int j = t + i * 256;
    dst[(size_t)b * DD + j] = (x[i] - m) * inv * g[j] + bb[j];
  }
}

// ---------- attention pipeline ----------
__global__ __launch_bounds__(256) void k_qp(const float* __restrict__ qln,
    const float* __restrict__ Wi, const float* __restrict__ bi, float* __restrict__ qp) {
  int idx = blockIdx.x * 4 + (threadIdx.x >> 6);
  int l = threadIdx.x & 63;
  int b = idx >> 10, n = idx & 1023;
  const float* xr = qln + (size_t)b * DD;
  const float* wr = Wi + (size_t)n * DD;
  float acc = 0.f;
#pragma unroll
  for (int k0 = 0; k0 < 1024; k0 += 64) acc += xr[k0 + l] * wr[k0 + l];
  acc = wred_sum(acc);
  if (l == 0) qp[idx] = acc + bi[n];
}

__global__ __launch_bounds__(256) void k_c0(const float* __restrict__ qp,
    const float* __restrict__ bi, float* __restrict__ c0) {
  int t = threadIdx.x;
  if (t < 64) {
    int b = t >> 3, h = t & 7;
    float a = 0.f;
#pragma unroll 8
    for (int d = 0; d < 128; d++)
      a += qp[b * 1024 + h * 128 + d] * bi[1024 + h * 128 + d];
    c0[t] = a;
  }
}

__global__ __launch_bounds__(256) void k_u(const float* __restrict__ qp,
    const float* __restrict__ Wi, float* __restrict__ u) {
  int h = blockIdx.x >> 4, kt = blockIdx.x & 15;
  int t = threadIdx.x;
  __shared__ float qs[8][128];
#pragma unroll
  for (int i = 0; i < 4; i++) {
    int f = t * 4 + i;
    int b = f >> 7, d = f & 127;
    qs[b][d] = qp[b * 1024 + h * 128 + d];
  }
  __syncthreads();
  int k = kt * 64 + (t & 63);
  int bh = t >> 6;
  const float* wkb = Wi + (size_t)(1024 + h * 128) * DD + k;
  float a0 = 0.f, a1 = 0.f;
#pragma unroll 8
  for (int d = 0; d < 128; d++) {
    float wv = wkb[(size_t)d * DD];
    a0 += qs[bh][d] * wv;
    a1 += qs[bh + 4][d] * wv;
  }
  u[(size_t)(bh * 8 + h) * DD + k] = a0;
  u[(size_t)((bh + 4) * 8 + h) * DD + k] = a1;
}

__global__ __launch_bounds__(256) void k_lg(const float* __restrict__ u,
    const bf16* __restrict__ kvbuf, const float* __restrict__ c0, f16* __restrict__ lg) {
  int b = blockIdx.x / 33, tile = blockIdx.x % 33;
  int p0 = tile * 32, t = threadIdx.x;
  __shared__ bf16 kvs[32 * 1032];
  __shared__ float us[8 * 1032];
  const bf16* kvb = kvbuf + (size_t)b * 1032 * DD;
#pragma unroll
  for (int i = 0; i < 16; i++) {
    int flat = (i * 256 + t) * 8;
    int row = flat >> 10, col = flat & 1023;
    int gp = p0 + row; if (gp > 1031) gp = 1031;
    *(v8bf*)(kvs + row * 1032 + col) = *(const v8bf*)(kvb + (size_t)gp * DD + col);
  }
#pragma unroll
  for (int i = 0; i < 8; i++) {
    int flat = (i * 256 + t) * 4;
    int row = flat >> 10, col = flat & 1023;
    *(v4f*)(us + row * 1032 + col) = *(const v4f*)(u + (size_t)(b * 8 + row) * DD + col);
  }
  __syncthreads();
  int pl = t >> 3, h = t & 7;
  if (p0 + pl < 1032) {
    float acc = 0.f;
#pragma unroll
    for (int k = 0; k < 1024; k += 8) {
      v8bf kv8 = *(const v8bf*)(kvs + pl * 1032 + k);
#pragma unroll
      for (int j = 0; j < 8; j++) acc += us[h * 1032 + k + j] * (float)kv8[j];
    }
    lg[(size_t)(b * 8 + h) * 1032 + p0 + pl] =
        (f16)((acc + c0[b * 8 + h]) * 0.08838834764831845f);
  }
}

__global__ __launch_bounds__(256) void k_sm(f16* __restrict__ lg) {
  int t = threadIdx.x, l = t & 63, w = t >> 6;
  f16* p = lg + (size_t)blockIdx.x * 1032;
  float x[5];
  float mx = -3.4e38f;
#pragma unroll
  for (int i = 0; i < 5; i++) {
    int idx = t + i * 256;
    if (idx < 1032) { x[i] = (float)p[idx]; mx = fmaxf(mx, x[i]); }
  }
  __shared__ float sh[4];
#pragma unroll
  for (int o = 32; o; o >>= 1) mx = fmaxf(mx, __shfl_down(mx, o, 64));
  if (l == 0) sh[w] = mx;
  __syncthreads();
  mx = fmaxf(fmaxf(sh[0], sh[1]), fmaxf(sh[2], sh[3]));
  __syncthreads();
  float sum = 0.f;
#pragma unroll
  for (int i = 0; i < 5; i++) {
    int idx = t + i * 256;
    if (idx < 1032) { x[i] = expf(x[i] - mx); sum += x[i]; }
  }
  sum = wred_sum(sum);
  if (l == 0) sh[w] = sum;
  __syncthreads();
  float inv = 1.0f / (sh[0] + sh[1] + sh[2] + sh[3]);
#pragma unroll
  for (int i = 0; i < 5; i++) {
    int idx = t + i * 256;
    if (idx < 1032) p[idx] = (f16)(x[i] * inv);
  }
}

__global__ __launch_bounds__(256) void k_s(const f16* __restrict__ lg,
    const bf16* __restrict__ kvbuf, bf16* __restrict__ s) {
  int b = blockIdx.x >> 4, kt = blockIdx.x & 15;
  int t = threadIdx.x;
  __shared__ f16 wl[8 * 1040];
  for (int h = 0; h < 8; h++)
    for (int i = t; i < 1032; i += 256)
      wl[h * 1040 + i] = lg[(size_t)(b * 8 + h) * 1032 + i];
  __syncthreads();
  int k = kt * 64 + (t & 63), h0 = t >> 6;
  const bf16* kvb = kvbuf + (size_t)b * 1032 * DD + k;
  float a0 = 0.f, a1 = 0.f;
#pragma unroll 4
  for (int p = 0; p < 1032; p++) {
    float kvv = (float)kvb[(size_t)p * DD];
    a0 += (float)wl[h0 * 1040 + p] * kvv;
    a1 += (float)wl[(h0 + 4) * 1040 + p] * kvv;
  }
  s[(size_t)(b * 8 + h0) * DD + k] = (bf16)a0;
  s[(size_t)(b * 8 + h0 + 4) * DD + k] = (bf16)a1;
}

__global__ __launch_bounds__(256) void k_ov(const bf16* __restrict__ s,
    const float* __restrict__ Wi, const float* __restrict__ bi, float* __restrict__ o) {
  int idx = blockIdx.x * 4 + (threadIdx.x >> 6);
  int l = threadIdx.x & 63;
  int b = idx >> 10, n = idx & 1023, h = n >> 7;
  const bf16* sr = s + (size_t)(b * 8 + h) * DD;
  const float* wr = Wi + (size_t)(2048 + n) * DD;
  float acc = 0.f;
#pragma unroll
  for (int k0 = 0; k0 < 1024; k0 += 64) acc += (float)sr[k0 + l] * wr[k0 + l];
  acc = wred_sum(acc);
  if (l == 0) o[idx] = acc + bi[2048 + n];
}

// ---------- tail GEMVs ----------
template <int MODE>
__global__ __launch_bounds__(256) void k_gemv(const float* __restrict__ xin,
    const float* __restrict__ W, const float* __restrict__ bias,
    const float* __restrict__ res, float* __restrict__ outf) {
  int idx = blockIdx.x * 4 + (threadIdx.x >> 6);
  int l = threadIdx.x & 63;
  int b = idx >> 10, n = idx & 1023;
  const float* xr = xin + (size_t)b * DD;
  const float* wr = W + (size_t)n * DD;
  float acc = 0.f;
#pragma unroll
  for (int k0 = 0; k0 < 1024; k0 += 64) acc += xr[k0 + l] * wr[k0 + l];
  acc = wred_sum(acc);
  if (l == 0) {
    float v = acc + bias[n];
    if (MODE == 0) outf[idx] = res[idx] + v;
    if (MODE == 1) outf[idx] = 0.5f * v * (1.0f + erff(v * 0.70710678118654752f));
    if (MODE == 2) outf[idx] = res[idx] + v;
    if (MODE == 3) outf[O_Y + idx] = v;
  }
}

extern "C" void kernel_launch(void* const* d_in, const int* in_sizes, int n_in,
                              void* d_out, int out_size, void* d_ws, size_t ws_size,
                              hipStream_t stream) {
  const float* x        = (const float*)d_in[0];
  const float* state_in = (const float*)d_in[1];
  const float* W_rg     = (const float*)d_in[2];
  const float* ln_moe_g = (const float*)d_in[3];
  const float* ln_moe_b = (const float*)d_in[4];
  const float* W_gate   = (const float*)d_in[5];
  const float* A_skew   = (const float*)d_in[6];
  const float* ln_sl_g  = (const float*)d_in[7];
  const float* ln_sl_b  = (const float*)d_in[8];
  const float* W_slot   = (const float*)d_in[9];
  const float* W_oe     = (const float*)d_in[10];
  const float* b_oe     = (const float*)d_in[11];
  const float* ln_q_g   = (const float*)d_in[12];
  const float* ln_q_b   = (const float*)d_in[13];
  const float* ln_kv_g  = (const float*)d_in[14];
  const float* ln_kv_b  = (const float*)d_in[15];
  const float* in_w     = (const float*)d_in[16];
  const float* in_b     = (const float*)d_in[17];
  const float* out_w    = (const float*)d_in[18];
  const float* out_b    = (const float*)d_in[19];
  const float* ln_f_g   = (const float*)d_in[20];
  const float* ln_f_b   = (const float*)d_in[21];
  const float* W_fc1    = (const float*)d_in[22];
  const float* b_fc1    = (const float*)d_in[23];
  const float* W_fc2    = (const float*)d_in[24];
  const float* b_fc2    = (const float*)d_in[25];
  const float* W_out    = (const float*)d_in[26];
  const float* b_out    = (const float*)d_in[27];

  char* ws = (char*)d_ws;
  bf16*  kvbuf    = (bf16*)(ws + W_KV);
  float* state_ws = (float*)(ws + W_STATE);
  float* u_buf    = (float*)(ws + W_STATE);
  bf16*  s_buf    = (bf16*)(ws + W_STATE);
  float* lat_last = (float*)(ws + W_LATL);
  float* qln      = (float*)(ws + W_QLN);
  float* c0       = (float*)(ws + W_QLN);
  float* r2       = (float*)(ws + W_R2);
  float* rsc      = (float*)(ws + W_RSC);
  float* ssc      = (float*)(ws + W_SSC);
  float* qp       = (float*)(ws + W_OATT);
  f16*   lg       = (f16*)(ws + W_OATT);
  float* o_attn   = (float*)(ws + W_OATT);
  float* lat1     = (float*)(ws + W_LAT1);
  float* lnffn    = (float*)(ws + W_LNFFN);
  float* h1       = (float*)(ws + W_H1);
  float* lat2     = (float*)(ws + W_LAT2);
  float* out = (float*)d_out;

  k_r2<<<1024, 256, 0, stream>>>(A_skew, r2);
  k_scores<<<64, 256, 0, stream>>>(state_in, W_rg, ln_sl_g, ln_sl_b, W_slot, rsc, ssc);
  k_gate<<<32, 256, 0, stream>>>(state_in, rsc, ln_moe_g, ln_moe_b, W_gate, out);
  k_state<<<8, 256, 0, stream>>>(state_in, rsc, ssc, r2, state_ws, out);
  k_gemm<<<dim3(8, 64), 256, 0, stream>>>(x, W_oe, b_oe, kvbuf, lat_last);
  k_ln<<<8256, 256, 0, stream>>>(kvbuf, state_ws, ln_kv_g, ln_kv_b, ln_q_g, ln_q_b, qln, lat_last);
  k_qp<<<2048, 256, 0, stream>>>(qln, in_w, in_b, qp);
  k_c0<<<1, 256, 0, stream>>>(qp, in_b, c0);
  k_u<<<128, 256, 0, stream>>>(qp, in_w, u_buf);
  k_lg<<<264, 256, 0, stream>>>(u_buf, kvbuf, c0, lg);
  k_sm<<<64, 256, 0, stream>>>(lg);
  k_s<<<128, 256, 0, stream>>>(lg, kvbuf, s_buf);
  k_ov<<<2048, 256, 0, stream>>>(s_buf, in_w, in_b, o_attn);
  k_gemv<0><<<2048, 256, 0, stream>>>(o_attn, out_w, out_b, lat_last, lat1);
  k_ln_row<<<8, 256, 0, stream>>>(lat1, ln_f_g, ln_f_b, lnffn);
  k_gemv<1><<<2048, 256, 0, stream>>>(lnffn, W_fc1, b_fc1, nullptr, h1);
  k_gemv<2><<<2048, 256, 0, stream>>>(h1, W_fc2, b_fc2, lat1, lat2);
  k_gemv<3><<<2048, 256, 0, stream>>>(lat2, W_out, b_out, nullptr, out);
}

// Round 4
// 377.408 us; speedup vs baseline: 1.4913x; 1.4768x over previous
//
#include <hip/hip_runtime.h>
#include <hip/hip_bf16.h>

typedef __bf16 bf16;
typedef _Float16 f16;
typedef __bf16 v8bf __attribute__((ext_vector_type(8)));
typedef float v4f __attribute__((ext_vector_type(4)));

// ---------- constants ----------
#define DD 1024
#define LN_EPS 1e-5f

// output element offsets (all f32 in d_out)
#define O_Y     0
#define O_STATE 8192
#define O_IDXE  73728
#define O_RIDX  73792
#define O_WIDX  73824

// ws byte offsets (total 17404416 B — exact round-5/7 layout, proven in-bounds)
#define W_KV      0ull                      // bf16 [8][1032][1024] 16908288
#define W_STATE   16908288ull               // f32  [8][8][1024]      262144 (PoolA: u f32 then s bf16)
#define W_LATL    17170432ull               // f32  [8][1024]          32768
#define W_QLN     17203200ull               // f32  [8][1024]  (c0[64] reuses after k_qp)
#define W_R2      17235968ull               // f32  [1024]
#define W_RSC     17240064ull               // f32  [64]
#define W_SSC     17240320ull               // f32  [64]
#define W_OATT    17240576ull               // PoolB 160KB: qp / lg(f16 132KB) / o_attn+lat1..lat2
#define W_LAT1    17273344ull
#define W_LNFFN   17306112ull
#define W_H1      17338880ull
#define W_LAT2    17371648ull

__device__ __forceinline__ float wred_sum(float v) {
#pragma unroll
  for (int o = 32; o; o >>= 1) v += __shfl_down(v, o, 64);
  return v;
}

__device__ __forceinline__ void top4_of8(const float* sc, int* ridx) {
  unsigned used = 0;
#pragma unroll
  for (int k = 0; k < 4; k++) {
    float best = -3.4e38f; int bi = 0;
    for (int s = 0; s < 8; s++)
      if (!((used >> s) & 1) && sc[s] > best) { best = sc[s]; bi = s; }
    used |= 1u << bi; ridx[k] = bi;
  }
}

// ---------- r2 = row norms of A_skew ----------
__global__ __launch_bounds__(256) void k_r2(const float* __restrict__ A, float* __restrict__ r2) {
  int row = blockIdx.x, t = threadIdx.x;
  const float* p = A + (size_t)row * DD;
  float s = 0.f;
  for (int j = t; j < DD; j += 256) { float x = p[j]; s += x * x; }
  s = wred_sum(s);
  __shared__ float sh[4];
  if ((t & 63) == 0) sh[t >> 6] = s;
  __syncthreads();
  if (t == 0) r2[row] = sh[0] + sh[1] + sh[2] + sh[3];
}

// ---------- read_scores + slot_scores ----------
__global__ __launch_bounds__(256) void k_scores(const float* __restrict__ state,
    const float* __restrict__ W_rg, const float* __restrict__ g_sl, const float* __restrict__ b_sl,
    const float* __restrict__ W_sl, float* __restrict__ rsc, float* __restrict__ ssc) {
  int row = blockIdx.x, t = threadIdx.x, l = t & 63, w = t >> 6;
  const float* p = state + (size_t)row * DD;
  float x[4]; float sum = 0.f, sq = 0.f, rs = 0.f;
#pragma unroll
  for (int i = 0; i < 4; i++) {
    int j = t + i * 256;
    x[i] = p[j];
    sum += x[i]; sq += x[i] * x[i];
    rs += x[i] * W_rg[j];
  }
  __shared__ float sh[3][4];
  sum = wred_sum(sum); sq = wred_sum(sq); rs = wred_sum(rs);
  if (l == 0) { sh[0][w] = sum; sh[1][w] = sq; sh[2][w] = rs; }
  __syncthreads();
  float m = (sh[0][0] + sh[0][1] + sh[0][2] + sh[0][3]) * (1.0f / 1024.0f);
  float var = (sh[1][0] + sh[1][1] + sh[1][2] + sh[1][3]) * (1.0f / 1024.0f) - m * m;
  float rsTot = sh[2][0] + sh[2][1] + sh[2][2] + sh[2][3];
  float inv = 1.0f / sqrtf(var + LN_EPS);
  __syncthreads();
  float ss = 0.f;
#pragma unroll
  for (int i = 0; i < 4; i++) {
    int j = t + i * 256;
    float ln = (x[i] - m) * inv * g_sl[j] + b_sl[j];
    ss += ln * W_sl[j];
  }
  ss = wred_sum(ss);
  if (l == 0) sh[0][w] = ss;
  __syncthreads();
  if (t == 0) { rsc[row] = rsTot; ssc[row] = sh[0][0] + sh[0][1] + sh[0][2] + sh[0][3]; }
}

// ---------- gate: LN_moe + gate logits + top2 -> idx_experts, read_idx (f32 out) ----------
__global__ __launch_bounds__(256) void k_gate(const float* __restrict__ state,
    const float* __restrict__ rsc, const float* __restrict__ g_moe, const float* __restrict__ b_moe,
    const float* __restrict__ Wg, float* __restrict__ out) {
  int b = blockIdx.x >> 2, k = blockIdx.x & 3;
  int t = threadIdx.x, l = t & 63, w = t >> 6;
  __shared__ float rs[8];
  __shared__ float red[2][4];
  __shared__ float gl[8];
  if (t < 8) rs[t] = rsc[b * 8 + t];
  __syncthreads();
  int ridx[4]; top4_of8(rs, ridx);
  int s = ridx[k];
  const float* p = state + (size_t)(b * 8 + s) * DD;
  float x[4]; float sum = 0.f, sq = 0.f;
#pragma unroll
  for (int i = 0; i < 4; i++) {
    int j = t + i * 256;
    x[i] = p[j]; sum += x[i]; sq += x[i] * x[i];
  }
  sum = wred_sum(sum); sq = wred_sum(sq);
  if (l == 0) { red[0][w] = sum; red[1][w] = sq; }
  __syncthreads();
  float m = (red[0][0] + red[0][1] + red[0][2] + red[0][3]) * (1.0f / 1024.0f);
  float var = (red[1][0] + red[1][1] + red[1][2] + red[1][3]) * (1.0f / 1024.0f) - m * m;
  float inv = 1.0f / sqrtf(var + LN_EPS);
  float lnv[4];
#pragma unroll
  for (int i = 0; i < 4; i++) {
    int j = t + i * 256;
    lnv[i] = (x[i] - m) * inv * g_moe[j] + b_moe[j];
  }
  __syncthreads();
  for (int e = 0; e < 8; e++) {
    float acc = 0.f;
#pragma unroll
    for (int i = 0; i < 4; i++) acc += lnv[i] * Wg[(size_t)e * DD + t + i * 256];
    acc = wred_sum(acc);
    if (l == 0) red[0][w] = acc;
    __syncthreads();
    if (t == 0) gl[e] = red[0][0] + red[0][1] + red[0][2] + red[0][3];
    __syncthreads();
  }
  if (t == 0) {
    int e0 = 0, e1 = 0; float b0 = -3.4e38f, b1 = -3.4e38f;
    for (int e = 0; e < 8; e++) {
      float v = gl[e];
      if (v > b0) { b1 = b0; e1 = e0; b0 = v; e0 = e; }
      else if (v > b1) { b1 = v; e1 = e; }
    }
    out[O_IDXE + (b * 4 + k) * 2 + 0] = (float)e0;
    out[O_IDXE + (b * 4 + k) * 2 + 1] = (float)e1;
    if (k == 0)
      for (int kk = 0; kk < 4; kk++) out[O_RIDX + b * 4 + kk] = (float)ridx[kk];
  }
}

// ---------- state update (f32 out) ----------
__global__ __launch_bounds__(256) void k_state(const float* __restrict__ state_in,
    const float* __restrict__ rsc, const float* __restrict__ ssc, const float* __restrict__ r2,
    float* __restrict__ state_ws, float* __restrict__ out) {
  int b = blockIdx.x, t = threadIdx.x;
  __shared__ float rs[8];
  if (t < 8) rs[t] = rsc[b * 8 + t];
  __syncthreads();
  int ridx[4]; top4_of8(rs, ridx);
  float lr[4];
#pragma unroll
  for (int k = 0; k < 4; k++) lr[k] = ssc[b * 8 + ridx[k]];
  int w0 = 0, w1 = 0; float b0 = -3.4e38f, b1 = -3.4e38f;
#pragma unroll
  for (int k = 0; k < 4; k++) {
    float v = lr[k];
    if (v > b0) { b1 = b0; w1 = w0; b0 = v; w0 = k; }
    else if (v > b1) { b1 = v; w1 = k; }
  }
  int wid0 = ridx[w0], wid1 = ridx[w1];
  float mx = fmaxf(lr[0], lr[1]);
  float e0 = expf(lr[0] - mx), e1 = expf(lr[1] - mx);
  float den = e0 + e1;
  float ws0 = e0 / den, ws1 = e1 / den;
  float resid = 1.0f - (ws0 + ws1);
#pragma unroll
  for (int i = 0; i < 4; i++) {
    int j = t + i * 256;
    float q = 1.0f - 0.03125f * r2[j];  // diag Cayley, c=0.125, O(c^4) dropped
    float lca = 0.f;
#pragma unroll
    for (int k = 0; k < 4; k++)
      lca += tanhf(state_in[(size_t)(b * 8 + ridx[k]) * DD + j] * q);
    float tj = tanhf(lca * 0.25f);
#pragma unroll
    for (int s = 0; s < 8; s++) {
      float a = (s == wid0) ? ws0 : ((s == wid1) ? ws1 : 0.0f);
      float v = a * tj + resid * state_in[(size_t)(b * 8 + s) * DD + j];
      state_ws[(size_t)(b * 8 + s) * DD + j] = v;
      out[O_STATE + (size_t)(b * 8 + s) * DD + j] = v;
    }
  }
  if (t == 0) {
    out[O_WIDX + b * 2 + 0] = (float)wid0;
    out[O_WIDX + b * 2 + 1] = (float)wid1;
  }
}

// ---------- MFMA BT GEMM, f32 inputs, cvt staging, XCD swizzle ----------
// Accumulator is 16 NAMED v4f variables (c00..c33) — no ext_vector array, no runtime
// indexing anywhere (rule #20: arrays with non-provably-static indexing get lowered
// to scratch; rounds 0-2 showed VGPR_Count=60 + ~900MB phantom WRITE_SIZE = the acc
// array spilling per K-iter). Epilogue stages each 32x128 slab through LDS and
// flushes 32B/lane contiguous. LDS chunk-XOR swizzle on stage+fragment reads.
#define MF(CC, AF, BF) CC = __builtin_amdgcn_mfma_f32_16x16x32_bf16(AF, BF, CC, 0, 0, 0)

__global__ __launch_bounds__(256, 2) void k_gemm(const float* __restrict__ A,
    const float* __restrict__ Bm, const float* __restrict__ bias, bf16* __restrict__ kvbuf,
    float* __restrict__ lat_last) {
  __shared__ bf16 As[128 * 32];
  __shared__ bf16 Bs[128 * 32];
  const int t = threadIdx.x, l = t & 63, w = t >> 6;
  const int lin = blockIdx.y * 8 + blockIdx.x;
  const int mb = ((lin & 7) << 3) | ((lin >> 3) & 7);   // 8 A-band blocks per XCD
  const int nb = lin >> 6;
  const int mbase = mb * 128, nbase = nb * 128;
  const int wm = (w >> 1) * 64, wn = (w & 1) * 64;
  const int lm = l & 15, lk4 = l >> 4;                  // fragment chunk 0..3

  v4f c00 = (v4f){0.f,0.f,0.f,0.f}, c01 = (v4f){0.f,0.f,0.f,0.f},
      c02 = (v4f){0.f,0.f,0.f,0.f}, c03 = (v4f){0.f,0.f,0.f,0.f},
      c10 = (v4f){0.f,0.f,0.f,0.f}, c11 = (v4f){0.f,0.f,0.f,0.f},
      c12 = (v4f){0.f,0.f,0.f,0.f}, c13 = (v4f){0.f,0.f,0.f,0.f},
      c20 = (v4f){0.f,0.f,0.f,0.f}, c21 = (v4f){0.f,0.f,0.f,0.f},
      c22 = (v4f){0.f,0.f,0.f,0.f}, c23 = (v4f){0.f,0.f,0.f,0.f},
      c30 = (v4f){0.f,0.f,0.f,0.f}, c31 = (v4f){0.f,0.f,0.f,0.f},
      c32 = (v4f){0.f,0.f,0.f,0.f}, c33 = (v4f){0.f,0.f,0.f,0.f};

  const int srow = t >> 2;          // 0..63
  const int sch = t & 3;            // staging chunk 0..3 (8 bf16 each)
  const int swA0 = srow * 32 + (sch ^ ((srow >> 1) & 3)) * 8;
  const int swA1 = (srow + 64) * 32 + (sch ^ (((srow + 64) >> 1) & 3)) * 8;
  // fragment swizzle: ((wm+i*16+lm)>>1)&3 == ((lm>>1)&3) since wm,i*16 have no bits <4
  const int fa_base = (wm + lm) * 32 + ((lk4 ^ ((lm >> 1) & 3)) * 8);
  const int fb_base = (wn + lm) * 32 + ((lk4 ^ ((lm >> 1) & 3)) * 8);

  for (int k0 = 0; k0 < 1024; k0 += 32) {
    const float* ap0 = A + (size_t)(mbase + srow) * 1024 + k0 + sch * 8;
    const float* ap1 = ap0 + (size_t)64 * 1024;
    const float* bp0 = Bm + (size_t)(nbase + srow) * 1024 + k0 + sch * 8;
    const float* bp1 = bp0 + (size_t)64 * 1024;
    v4f a00 = *(const v4f*)ap0, a01 = *(const v4f*)(ap0 + 4);
    v4f a10 = *(const v4f*)ap1, a11 = *(const v4f*)(ap1 + 4);
    v8bf pa0, pa1;
#pragma unroll
    for (int r = 0; r < 4; r++) { pa0[r] = (bf16)a00[r]; pa0[4 + r] = (bf16)a01[r]; }
#pragma unroll
    for (int r = 0; r < 4; r++) { pa1[r] = (bf16)a10[r]; pa1[4 + r] = (bf16)a11[r]; }
    v4f b00 = *(const v4f*)bp0, b01 = *(const v4f*)(bp0 + 4);
    v4f b10 = *(const v4f*)bp1, b11 = *(const v4f*)(bp1 + 4);
    v8bf pb0, pb1;
#pragma unroll
    for (int r = 0; r < 4; r++) { pb0[r] = (bf16)b00[r]; pb0[4 + r] = (bf16)b01[r]; }
#pragma unroll
    for (int r = 0; r < 4; r++) { pb1[r] = (bf16)b10[r]; pb1[4 + r] = (bf16)b11[r]; }
    __syncthreads();
    *(v8bf*)(As + swA0) = pa0;
    *(v8bf*)(As + swA1) = pa1;
    *(v8bf*)(Bs + swA0) = pb0;
    *(v8bf*)(Bs + swA1) = pb1;
    __syncthreads();
    v8bf af0 = *(const v8bf*)(As + fa_base);
    v8bf af1 = *(const v8bf*)(As + fa_base + 512);
    v8bf af2 = *(const v8bf*)(As + fa_base + 1024);
    v8bf af3 = *(const v8bf*)(As + fa_base + 1536);
    v8bf bq0 = *(const v8bf*)(Bs + fb_base);
    v8bf bq1 = *(const v8bf*)(Bs + fb_base + 512);
    v8bf bq2 = *(const v8bf*)(Bs + fb_base + 1024);
    v8bf bq3 = *(const v8bf*)(Bs + fb_base + 1536);
    MF(c00, af0, bq0); MF(c01, af0, bq1); MF(c02, af0, bq2); MF(c03, af0, bq3);
    MF(c10, af1, bq0); MF(c11, af1, bq1); MF(c12, af1, bq2); MF(c13, af1, bq3);
    MF(c20, af2, bq0); MF(c21, af2, bq1); MF(c22, af2, bq2); MF(c23, af2, bq3);
    MF(c30, af3, bq0); MF(c31, af3, bq1); MF(c32, af3, bq2); MF(c33, af3, bq3);
  }

  // ---- epilogue: LDS-staged coalesced stores (reuse As: 32 rows x 128 cols = 8KB) ----
  bf16* ot = As;
  const int band = w >> 1;
  const int er = (l >> 4) * 4;
  const int frr = t >> 3, fcc = (t & 7) * 16;

#define EPI_ONE(ii, jj, CC) do { \
    _Pragma("unroll") \
    for (int r = 0; r < 4; r++) { \
      int lrow = band * 16 + er + r; \
      int lcol = wn + (jj) * 16 + lm; \
      int grow = mbase + band * 64 + (ii) * 16 + er + r; \
      int col = nbase + lcol; \
      int tok = grow & 1023, bb = grow >> 10; \
      int i2 = col & 511; \
      float fdiv = exp2f((float)i2 * (3.0f / 512.0f)); \
      float aarg = (float)tok / fdiv; \
      float pe = (col < 512) ? sinf(aarg) : cosf(aarg); \
      float v = CC[r] + bias[col] + pe; \
      ot[lrow * 128 + lcol] = (bf16)v; \
      if (tok == 1023) lat_last[(size_t)bb * 1024 + col] = v; \
    } \
  } while (0)

#define EPI_SLAB(ii, C0, C1, C2, C3) do { \
    __syncthreads(); \
    EPI_ONE(ii, 0, C0); EPI_ONE(ii, 1, C1); EPI_ONE(ii, 2, C2); EPI_ONE(ii, 3, C3); \
    __syncthreads(); \
    { int grow = mbase + (frr >> 4) * 64 + (ii) * 16 + (frr & 15); \
      int tok = grow & 1023, bb = grow >> 10; \
      v8bf d0 = *(const v8bf*)(ot + frr * 128 + fcc); \
      v8bf d1 = *(const v8bf*)(ot + frr * 128 + fcc + 8); \
      bf16* dst = kvbuf + ((size_t)bb * 1032 + tok) * 1024 + nbase + fcc; \
      *(v8bf*)dst = d0; \
      *(v8bf*)(dst + 8) = d1; } \
  } while (0)

  EPI_SLAB(0, c00, c01, c02, c03);
  EPI_SLAB(1, c10, c11, c12, c13);
  EPI_SLAB(2, c20, c21, c22, c23);
  EPI_SLAB(3, c30, c31, c32, c33);
#undef EPI_ONE
#undef EPI_SLAB
}

// ---------- LN (in-place on kv token rows; state rows from f32; q row from f32 lat_last) ----------
__global__ __launch_bounds__(256) void k_ln(bf16* __restrict__ kvbuf,
    const float* __restrict__ state_ws, const float* __restrict__ gkv, const float* __restrict__ bkv,
    const float* __restrict__ gq, const float* __restrict__ bq,
    float* __restrict__ qln, const float* __restrict__ lat_last) {
  int r = blockIdx.x, t = threadIdx.x, l = t & 63, w = t >> 6;
  int b = r / 1032, p = r % 1032;
  bf16* row = kvbuf + ((size_t)b * 1032 + p) * DD;
  float x[4]; float sum = 0.f, sq = 0.f;
  if (p == 1023) {
    const float* src = lat_last + (size_t)b * DD;
#pragma unroll
    for (int i = 0; i < 4; i++) {
      int j = t + i * 256;
      x[i] = src[j]; sum += x[i]; sq += x[i] * x[i];
    }
  } else if (p < 1024) {
#pragma unroll
    for (int i = 0; i < 4; i++) {
      int j = t + i * 256;
      x[i] = (float)row[j]; sum += x[i]; sq += x[i] * x[i];
    }
  } else {
    const float* src = state_ws + ((size_t)b * 8 + (p - 1024)) * DD;
#pragma unroll
    for (int i = 0; i < 4; i++) {
      int j = t + i * 256;
      x[i] = src[j]; sum += x[i]; sq += x[i] * x[i];
    }
  }
  __shared__ float sh[2][4];
  sum = wred_sum(sum); sq = wred_sum(sq);
  if (l == 0) { sh[0][w] = sum; sh[1][w] = sq; }
  __syncthreads();
  float m = (sh[0][0] + sh[0][1] + sh[0][2] + sh[0][3]) * (1.0f / 1024.0f);
  float var = (sh[1][0] + sh[1][1] + sh[1][2] + sh[1][3]) * (1.0f / 1024.0f) - m * m;
  float inv = 1.0f / sqrtf(var + LN_EPS);
  if (p == 1023) {
#pragma unroll
    for (int i = 0; i < 4; i++) {
      int j = t + i * 256;
      qln[(size_t)b * DD + j] = (x[i] - m) * inv * gq[j] + bq[j];
    }
  }
#pragma unroll
  for (int i = 0; i < 4; i++) {
    int j = t + i * 256;
    row[j] = (bf16)((x[i] - m) * inv * gkv[j] + bkv[j]);
  }
}

// ---------- LN of one f32 row per block (ffn pre-LN) ----------
__global__ __launch_bounds__(256) void k_ln_row(const float* __restrict__ src,
    const float* __restrict__ g, const float* __restrict__ bb, float* __restrict__ dst) {
  int b = blockIdx.x, t = threadIdx.x, l = t & 63, w = t >> 6;
  const float* p = src + (size_t)b * DD;
  float x[4]; float sum = 0.f, sq = 0.f;
#pragma unroll
  for (int i = 0; i < 4; i++) {
    int j = t + i * 256;
    x[i] = p[j]; sum += x[i]; sq += x[i] * x[i];
  }
  __shared__ float sh[2][4];
  sum = wred_sum(sum); sq = wred_sum(sq);
  if (l == 0) { sh[0][w] = sum; sh[1][w] = sq; }
  __syncthreads();
  float m = (sh[0][0] + sh[0][1] + sh[0][2] + sh[0][3]) * (1.0f / 1024.0f);
  float var = (sh[1][0] + sh[1][1] + sh[1][2] + sh[1][3]) * (1.0f / 1024.0f) - m * m;
  float inv = 1.0f / sqrtf(var + LN_EPS);
#pragma unroll
  for (int i = 0; i < 4; i++) {
    int j = t + i * 256;
    dst[(size_t)b * DD + j] = (x[i] - m) * inv * g[j] + bb[j];
  }
}

// ---------- attention pipeline ----------
__global__ __launch_bounds__(256) void k_qp(const float* __restrict__ qln,
    const float* __restrict__ Wi, const float* __restrict__ bi, float* __restrict__ qp) {
  int idx = blockIdx.x * 4 + (threadIdx.x >> 6);
  int l = threadIdx.x & 63;
  int b = idx >> 10, n = idx & 1023;
  const float* xr = qln + (size_t)b * DD;
  const float* wr = Wi + (size_t)n * DD;
  float acc = 0.f;
#pragma unroll
  for (int k0 = 0; k0 < 1024; k0 += 64) acc += xr[k0 + l] * wr[k0 + l];
  acc = wred_sum(acc);
  if (l == 0) qp[idx] = acc + bi[n];
}

__global__ __launch_bounds__(256) void k_c0(const float* __restrict__ qp,
    const float* __restrict__ bi, float* __restrict__ c0) {
  int t = threadIdx.x;
  if (t < 64) {
    int b = t >> 3, h = t & 7;
    float a = 0.f;
#pragma unroll 8
    for (int d = 0; d < 128; d++)
      a += qp[b * 1024 + h * 128 + d] * bi[1024 + h * 128 + d];
    c0[t] = a;
  }
}

__global__ __launch_bounds__(256) void k_u(const float* __restrict__ qp,
    const float* __restrict__ Wi, float* __restrict__ u) {
  int h = blockIdx.x >> 4, kt = blockIdx.x & 15;
  int t = threadIdx.x;
  __shared__ float qs[8][128];
#pragma unroll
  for (int i = 0; i < 4; i++) {
    int f = t * 4 + i;
    int b = f >> 7, d = f & 127;
    qs[b][d] = qp[b * 1024 + h * 128 + d];
  }
  __syncthreads();
  int k = kt * 64 + (t & 63);
  int bh = t >> 6;
  const float* wkb = Wi + (size_t)(1024 + h * 128) * DD + k;
  float a0 = 0.f, a1 = 0.f;
#pragma unroll 8
  for (int d = 0; d < 128; d++) {
    float wv = wkb[(size_t)d * DD];
    a0 += qs[bh][d] * wv;
    a1 += qs[bh + 4][d] * wv;
  }
  u[(size_t)(bh * 8 + h) * DD + k] = a0;
  u[(size_t)((bh + 4) * 8 + h) * DD + k] = a1;
}

__global__ __launch_bounds__(256) void k_lg(const float* __restrict__ u,
    const bf16* __restrict__ kvbuf, const float* __restrict__ c0, f16* __restrict__ lg) {
  int b = blockIdx.x / 33, tile = blockIdx.x % 33;
  int p0 = tile * 32, t = threadIdx.x;
  __shared__ bf16 kvs[32 * 1032];
  __shared__ float us[8 * 1032];
  const bf16* kvb = kvbuf + (size_t)b * 1032 * DD;
#pragma unroll
  for (int i = 0; i < 16; i++) {
    int flat = (i * 256 + t) * 8;
    int row = flat >> 10, col = flat & 1023;
    int gp = p0 + row; if (gp > 1031) gp = 1031;
    *(v8bf*)(kvs + row * 1032 + col) = *(const v8bf*)(kvb + (size_t)gp * DD + col);
  }
#pragma unroll
  for (int i = 0; i < 8; i++) {
    int flat = (i * 256 + t) * 4;
    int row = flat >> 10, col = flat & 1023;
    *(v4f*)(us + row * 1032 + col) = *(const v4f*)(u + (size_t)(b * 8 + row) * DD + col);
  }
  __syncthreads();
  int pl = t >> 3, h = t & 7;
  if (p0 + pl < 1032) {
    float acc = 0.f;
#pragma unroll
    for (int k = 0; k < 1024; k += 8) {
      v8bf kv8 = *(const v8bf*)(kvs + pl * 1032 + k);
#pragma unroll
      for (int j = 0; j < 8; j++) acc += us[h * 1032 + k + j] * (float)kv8[j];
    }
    lg[(size_t)(b * 8 + h) * 1032 + p0 + pl] =
        (f16)((acc + c0[b * 8 + h]) * 0.08838834764831845f);
  }
}

__global__ __launch_bounds__(256) void k_sm(f16* __restrict__ lg) {
  int t = threadIdx.x, l = t & 63, w = t >> 6;
  f16* p = lg + (size_t)blockIdx.x * 1032;
  float x[5];
  float mx = -3.4e38f;
#pragma unroll
  for (int i = 0; i < 5; i++) {
    int idx = t + i * 256;
    if (idx < 1032) { x[i] = (float)p[idx]; mx = fmaxf(mx, x[i]); }
  }
  __shared__ float sh[4];
#pragma unroll
  for (int o = 32; o; o >>= 1) mx = fmaxf(mx, __shfl_down(mx, o, 64));
  if (l == 0) sh[w] = mx;
  __syncthreads();
  mx = fmaxf(fmaxf(sh[0], sh[1]), fmaxf(sh[2], sh[3]));
  __syncthreads();
  float sum = 0.f;
#pragma unroll
  for (int i = 0; i < 5; i++) {
    int idx = t + i * 256;
    if (idx < 1032) { x[i] = expf(x[i] - mx); sum += x[i]; }
  }
  sum = wred_sum(sum);
  if (l == 0) sh[w] = sum;
  __syncthreads();
  float inv = 1.0f / (sh[0] + sh[1] + sh[2] + sh[3]);
#pragma unroll
  for (int i = 0; i < 5; i++) {
    int idx = t + i * 256;
    if (idx < 1032) p[idx] = (f16)(x[i] * inv);
  }
}

__global__ __launch_bounds__(256) void k_s(const f16* __restrict__ lg,
    const bf16* __restrict__ kvbuf, bf16* __restrict__ s) {
  int b = blockIdx.x >> 4, kt = blockIdx.x & 15;
  int t = threadIdx.x;
  __shared__ f16 wl[8 * 1040];
  for (int h = 0; h < 8; h++)
    for (int i = t; i < 1032; i += 256)
      wl[h * 1040 + i] = lg[(size_t)(b * 8 + h) * 1032 + i];
  __syncthreads();
  int k = kt * 64 + (t & 63), h0 = t >> 6;
  const bf16* kvb = kvbuf + (size_t)b * 1032 * DD + k;
  float a0 = 0.f, a1 = 0.f;
#pragma unroll 4
  for (int p = 0; p < 1032; p++) {
    float kvv = (float)kvb[(size_t)p * DD];
    a0 += (float)wl[h0 * 1040 + p] * kvv;
    a1 += (float)wl[(h0 + 4) * 1040 + p] * kvv;
  }
  s[(size_t)(b * 8 + h0) * DD + k] = (bf16)a0;
  s[(size_t)(b * 8 + h0 + 4) * DD + k] = (bf16)a1;
}

__global__ __launch_bounds__(256) void k_ov(const bf16* __restrict__ s,
    const float* __restrict__ Wi, const float* __restrict__ bi, float* __restrict__ o) {
  int idx = blockIdx.x * 4 + (threadIdx.x >> 6);
  int l = threadIdx.x & 63;
  int b = idx >> 10, n = idx & 1023, h = n >> 7;
  const bf16* sr = s + (size_t)(b * 8 + h) * DD;
  const float* wr = Wi + (size_t)(2048 + n) * DD;
  float acc = 0.f;
#pragma unroll
  for (int k0 = 0; k0 < 1024; k0 += 64) acc += (float)sr[k0 + l] * wr[k0 + l];
  acc = wred_sum(acc);
  if (l == 0) o[idx] = acc + bi[2048 + n];
}

// ---------- tail GEMVs ----------
template <int MODE>
__global__ __launch_bounds__(256) void k_gemv(const float* __restrict__ xin,
    const float* __restrict__ W, const float* __restrict__ bias,
    const float* __restrict__ res, float* __restrict__ outf) {
  int idx = blockIdx.x * 4 + (threadIdx.x >> 6);
  int l = threadIdx.x & 63;
  int b = idx >> 10, n = idx & 1023;
  const float* xr = xin + (size_t)b * DD;
  const float* wr = W + (size_t)n * DD;
  float acc = 0.f;
#pragma unroll
  for (int k0 = 0; k0 < 1024; k0 += 64) acc += xr[k0 + l] * wr[k0 + l];
  acc = wred_sum(acc);
  if (l == 0) {
    float v = acc + bias[n];
    if (MODE == 0) outf[idx] = res[idx] + v;
    if (MODE == 1) outf[idx] = 0.5f * v * (1.0f + erff(v * 0.70710678118654752f));
    if (MODE == 2) outf[idx] = res[idx] + v;
    if (MODE == 3) outf[O_Y + idx] = v;
  }
}

extern "C" void kernel_launch(void* const* d_in, const int* in_sizes, int n_in,
                              void* d_out, int out_size, void* d_ws, size_t ws_size,
                              hipStream_t stream) {
  const float* x        = (const float*)d_in[0];
  const float* state_in = (const float*)d_in[1];
  const float* W_rg     = (const float*)d_in[2];
  const float* ln_moe_g = (const float*)d_in[3];
  const float* ln_moe_b = (const float*)d_in[4];
  const float* W_gate   = (const float*)d_in[5];
  const float* A_skew   = (const float*)d_in[6];
  const float* ln_sl_g  = (const float*)d_in[7];
  const float* ln_sl_b  = (const float*)d_in[8];
  const float* W_slot   = (const float*)d_in[9];
  const float* W_oe     = (const float*)d_in[10];
  const float* b_oe     = (const float*)d_in[11];
  const float* ln_q_g   = (const float*)d_in[12];
  const float* ln_q_b   = (const float*)d_in[13];
  const float* ln_kv_g  = (const float*)d_in[14];
  const float* ln_kv_b  = (const float*)d_in[15];
  const float* in_w     = (const float*)d_in[16];
  const float* in_b     = (const float*)d_in[17];
  const float* out_w    = (const float*)d_in[18];
  const float* out_b    = (const float*)d_in[19];
  const float* ln_f_g   = (const float*)d_in[20];
  const float* ln_f_b   = (const float*)d_in[21];
  const float* W_fc1    = (const float*)d_in[22];
  const float* b_fc1    = (const float*)d_in[23];
  const float* W_fc2    = (const float*)d_in[24];
  const float* b_fc2    = (const float*)d_in[25];
  const float* W_out    = (const float*)d_in[26];
  const float* b_out    = (const float*)d_in[27];

  char* ws = (char*)d_ws;
  bf16*  kvbuf    = (bf16*)(ws + W_KV);
  float* state_ws = (float*)(ws + W_STATE);
  float* u_buf    = (float*)(ws + W_STATE);
  bf16*  s_buf    = (bf16*)(ws + W_STATE);
  float* lat_last = (float*)(ws + W_LATL);
  float* qln      = (float*)(ws + W_QLN);
  float* c0       = (float*)(ws + W_QLN);
  float* r2       = (float*)(ws + W_R2);
  float* rsc      = (float*)(ws + W_RSC);
  float* ssc      = (float*)(ws + W_SSC);
  float* qp       = (float*)(ws + W_OATT);
  f16*   lg       = (f16*)(ws + W_OATT);
  float* o_attn   = (float*)(ws + W_OATT);
  float* lat1     = (float*)(ws + W_LAT1);
  float* lnffn    = (float*)(ws + W_LNFFN);
  float* h1       = (float*)(ws + W_H1);
  float* lat2     = (float*)(ws + W_LAT2);
  float* out = (float*)d_out;

  k_r2<<<1024, 256, 0, stream>>>(A_skew, r2);
  k_scores<<<64, 256, 0, stream>>>(state_in, W_rg, ln_sl_g, ln_sl_b, W_slot, rsc, ssc);
  k_gate<<<32, 256, 0, stream>>>(state_in, rsc, ln_moe_g, ln_moe_b, W_gate, out);
  k_state<<<8, 256, 0, stream>>>(state_in, rsc, ssc, r2, state_ws, out);
  k_gemm<<<dim3(8, 64), 256, 0, stream>>>(x, W_oe, b_oe, kvbuf, lat_last);
  k_ln<<<8256, 256, 0, stream>>>(kvbuf, state_ws, ln_kv_g, ln_kv_b, ln_q_g, ln_q_b, qln, lat_last);
  k_qp<<<2048, 256, 0, stream>>>(qln, in_w, in_b, qp);
  k_c0<<<1, 256, 0, stream>>>(qp, in_b, c0);
  k_u<<<128, 256, 0, stream>>>(qp, in_w, u_buf);
  k_lg<<<264, 256, 0, stream>>>(u_buf, kvbuf, c0, lg);
  k_sm<<<64, 256, 0, stream>>>(lg);
  k_s<<<128, 256, 0, stream>>>(lg, kvbuf, s_buf);
  k_ov<<<2048, 256, 0, stream>>>(s_buf, in_w, in_b, o_attn);
  k_gemv<0><<<2048, 256, 0, stream>>>(o_attn, out_w, out_b, lat_last, lat1);
  k_ln_row<<<8, 256, 0, stream>>>(lat1, ln_f_g, ln_f_b, lnffn);
  k_gemv<1><<<2048, 256, 0, stream>>>(lnffn, W_fc1, b_fc1, nullptr, h1);
  k_gemv<2><<<2048, 256, 0, stream>>>(h1, W_fc2, b_fc2, lat1, lat2);
  k_gemv<3><<<2048, 256, 0, stream>>>(lat2, W_out, b_out, nullptr, out);
}